// Round 2
// baseline (1278.615 us; speedup 1.0000x reference)
//
#include <hip/hip_runtime.h>

// Elman RNN fused kernel.
// B=262144, T=10, I=1, H=32.
// out = [outs (B*T floats)] ++ [h_last (B*H floats)]
//
// One thread per batch element. h kept in registers (fully unrolled,
// compile-time indices only). All weight reads are wave-uniform ->
// compiler emits scalar loads (SGPR operands to v_fmac), so the inner
// 32x32 loop is pure VALU FMA with zero LDS traffic.

#define RNN_B 262144
#define RNN_T 10
#define RNN_H 32

__device__ __forceinline__ float fast_tanh(float a) {
    // tanh(a) = 1 - 2/(exp(2a)+1); exp(2a) = exp2(a * 2*log2(e))
    // Saturates correctly: a>>0 -> ez=inf -> r=0 -> 1.0; a<<0 -> ez=0 -> r=1 -> -1.0
    float ez = __builtin_amdgcn_exp2f(a * 2.885390081777927f);
    float r  = __builtin_amdgcn_rcpf(ez + 1.0f);
    return fmaf(-2.0f, r, 1.0f);
}

__global__ __launch_bounds__(256) void rnn_kernel(
    const float* __restrict__ x,     // [B,T]  (I==1)
    const float* __restrict__ h0,    // [B,H]
    const float* __restrict__ Wih,   // [H]    (I==1)
    const float* __restrict__ Whh,   // [H,H] row-major: Whh[j*H+k]
    const float* __restrict__ bih,   // [H]
    const float* __restrict__ bhh,   // [H]
    const float* __restrict__ Wout,  // [H]
    const float* __restrict__ bout,  // [1]
    float* __restrict__ out)         // [B*T] ++ [B*H]
{
    const int b = blockIdx.x * blockDim.x + threadIdx.x;

    // Load initial hidden state (per-thread contiguous 128B).
    float h[RNN_H];
    {
        const float4* hp = reinterpret_cast<const float4*>(h0 + (size_t)b * RNN_H);
        #pragma unroll
        for (int q = 0; q < RNN_H / 4; ++q) {
            float4 v = hp[q];
            h[q * 4 + 0] = v.x;
            h[q * 4 + 1] = v.y;
            h[q * 4 + 2] = v.z;
            h[q * 4 + 3] = v.w;
        }
    }

    const float* xp = x + (size_t)b * RNN_T;
    float*       op = out + (size_t)b * RNN_T;
    const float  bo = bout[0];

    #pragma unroll 1   // keep the t-loop rolled: ~1.2K-instr body stays in I-cache
    for (int t = 0; t < RNN_T; ++t) {
        const float xw = xp[t];

        float hn[RNN_H];
        #pragma unroll
        for (int j = 0; j < RNN_H; ++j) {
            // Wih[j], bih[j]+bhh[j] are wave-uniform -> SGPRs, hoisted by compiler.
            float a = fmaf(xw, Wih[j], bih[j] + bhh[j]);
            #pragma unroll
            for (int k = 0; k < RNN_H; ++k)
                a = fmaf(Whh[j * RNN_H + k], h[k], a);
            hn[j] = fast_tanh(a);
        }

        float o = bo;
        #pragma unroll
        for (int j = 0; j < RNN_H; ++j) {
            h[j] = hn[j];
            o = fmaf(hn[j], Wout[j], o);
        }
        op[t] = o;
    }

    // Final hidden state, per-thread contiguous 128B.
    float4* hlp = reinterpret_cast<float4*>(out + (size_t)RNN_B * RNN_T + (size_t)b * RNN_H);
    #pragma unroll
    for (int q = 0; q < RNN_H / 4; ++q) {
        float4 v;
        v.x = h[q * 4 + 0];
        v.y = h[q * 4 + 1];
        v.z = h[q * 4 + 2];
        v.w = h[q * 4 + 3];
        hlp[q] = v;
    }
}

extern "C" void kernel_launch(void* const* d_in, const int* in_sizes, int n_in,
                              void* d_out, int out_size, void* d_ws, size_t ws_size,
                              hipStream_t stream) {
    const float* x    = (const float*)d_in[0];
    const float* h0   = (const float*)d_in[1];
    const float* Wih  = (const float*)d_in[2];
    const float* Whh  = (const float*)d_in[3];
    const float* bih  = (const float*)d_in[4];
    const float* bhh  = (const float*)d_in[5];
    const float* Wout = (const float*)d_in[6];
    const float* bout = (const float*)d_in[7];
    float* out = (float*)d_out;

    // B from the harness (h0 has B*H elements); B is 262144 for this problem
    // and is guaranteed a multiple of 256 (1024 blocks).
    const int B = in_sizes[1] / RNN_H;
    dim3 grid(B / 256);
    dim3 block(256);
    hipLaunchKernelGGL(rnn_kernel, grid, block, 0, stream,
                       x, h0, Wih, Whh, bih, bhh, Wout, bout, out);
}

// Round 4
// 134.353 us; speedup vs baseline: 9.5168x; 9.5168x over previous
//
#include <hip/hip_runtime.h>

// Elman RNN via split-bf16 MFMA.  B=262144, T=10, I=1, H=32.
// out = [outs (B*T floats)] ++ [h_last (B*H floats)]
//
// Round-2 diagnosis: the scalar (thread-per-batch) kernel was bound by
// per-element wave-uniform weight fetch (~71 cyc/weight through the scalar
// path), 36x over the FMA floor. Cure: keep Whh lane-resident in VGPRs as
// MFMA A-fragments (loaded ONCE), and compute D[hdim][batch] = Whh * h^T
// per 32-batch wave tile with mfma_f32_32x32x16_bf16, split-bf16 (hi+lo)
// for ~fp32 accuracy. Next-step B-fragments are rebuilt in-register from
// the D layout via 8 packed-bf16 shfl_xor(32) lane-pair exchanges.
//
// Layouts (C/D guide-verified for 32x32x16 bf16; A/B standard CDNA):
//   C/D: col = lane&31, row = (reg&3) + 8*(reg>>2) + 4*(lane>>5)
//   A:   lane holds A[row=lane&31][k = (lane>>5)*8 + j], j=0..7 (k-pairs per VGPR)
//   B:   lane holds B[k = (lane>>5)*8 + j][col=lane&31]

#define RNN_T 10
#define RNN_H 32

typedef __attribute__((ext_vector_type(4))) unsigned int u32x4;
typedef __attribute__((ext_vector_type(8))) short s16x8;
typedef __attribute__((ext_vector_type(16))) float f32x16;

static __device__ __forceinline__ float fast_tanh(float a) {
    // tanh(a) = 1 - 2/(exp(2a)+1); saturates correctly at +-inf.
    float ez = __builtin_amdgcn_exp2f(a * 2.885390081777927f);
    float r  = __builtin_amdgcn_rcpf(ez + 1.0f);
    return fmaf(-2.0f, r, 1.0f);
}

// pack bf16-trunc(f0) [low 16] and bf16-trunc(f1) [high 16] into one u32
static __device__ __forceinline__ unsigned pack_hi_pair(float f0, float f1) {
    return (__float_as_uint(f1) & 0xffff0000u) | (__float_as_uint(f0) >> 16);
}
static __device__ __forceinline__ float trunc_bf16_f32(float f) {
    return __uint_as_float(__float_as_uint(f) & 0xffff0000u);
}

static __device__ __forceinline__ f32x16 mfma_bf16(u32x4 a, u32x4 b, f32x16 c) {
    return __builtin_amdgcn_mfma_f32_32x32x16_bf16(
        __builtin_bit_cast(s16x8, a), __builtin_bit_cast(s16x8, b), c, 0, 0, 0);
}

// load 8 consecutive floats, split into bf16 hi fragment + bf16 residual fragment
static __device__ __forceinline__ void load_split8(const float* __restrict__ p,
                                                   u32x4& hi4, u32x4& lo4) {
    float4 w0 = *reinterpret_cast<const float4*>(p);
    float4 w1 = *reinterpret_cast<const float4*>(p + 4);
    float w[8] = {w0.x, w0.y, w0.z, w0.w, w1.x, w1.y, w1.z, w1.w};
    #pragma unroll
    for (int i = 0; i < 4; ++i) {
        float f0 = w[2 * i], f1 = w[2 * i + 1];
        hi4[i] = pack_hi_pair(f0, f1);
        lo4[i] = pack_hi_pair(f0 - trunc_bf16_f32(f0), f1 - trunc_bf16_f32(f1));
    }
}

__global__ __launch_bounds__(256) void rnn_mfma(
    const float* __restrict__ x,     // [B,T]
    const float* __restrict__ h0,    // [B,H]
    const float* __restrict__ Wih,   // [H]
    const float* __restrict__ Whh,   // [H,H]
    const float* __restrict__ bih,   // [H]
    const float* __restrict__ bhh,   // [H]
    const float* __restrict__ Wout,  // [H]
    const float* __restrict__ bout,  // [1]
    float* __restrict__ out,         // [B*T] ++ [B*H]
    int B)
{
    const int tid  = threadIdx.x;
    const int lane = tid & 63;
    const int l31  = lane & 31;
    const int hi   = lane >> 5;            // 0 (lanes 0-31) or 1 (lanes 32-63)
    const bool lo_lane = (hi == 0);
    const int wave = tid >> 6;             // 0..3
    const int tile = blockIdx.x * 4 + wave;
    const int b    = tile * 32 + l31;      // batch (= D column) this lane owns
    const int kb   = hi * 8;               // this lane's k-chunk within an operand

    // ---- A fragments: Whh, split hi/lo, both K-halves. Loaded ONCE. ----
    u32x4 A1h, A1l, A2h, A2l;
    load_split8(Whh + l31 * RNN_H + 0  + kb, A1h, A1l);   // k = 0..15
    load_split8(Whh + l31 * RNN_H + 16 + kb, A2h, A2l);   // k = 16..31

    // ---- initial B fragments from h0 ----
    u32x4 B1h, B1l, B2h, B2l;
    load_split8(h0 + (size_t)b * RNN_H + 0  + kb, B1h, B1l);
    load_split8(h0 + (size_t)b * RNN_H + 16 + kb, B2h, B2l);

    // ---- per-reg row constants: row(r) = (r&3) + 8*(r>>2) + 4*hi ----
    float wih_r[16], bias_r[16], wout_r[16];
    #pragma unroll
    for (int r = 0; r < 16; ++r) {
        int row = (r & 3) + 8 * (r >> 2) + 4 * hi;
        wih_r[r]  = Wih[row];
        bias_r[r] = bih[row] + bhh[row];
        wout_r[r] = Wout[row];
    }

    // ---- x values for this batch, all T (lanes l and l+32 duplicate: fine) ----
    float xw[RNN_T];
    #pragma unroll
    for (int t = 0; t < RNN_T; ++t) xw[t] = x[(size_t)b * RNN_T + t];

    const float bo = bout[0];
    float h[16];

    #pragma unroll
    for (int t = 0; t < RNN_T; ++t) {
        // base: acc[r] = xw*Wih[row] + (bih+bhh)[row]  (serves as MFMA C-in)
        f32x16 acc;
        #pragma unroll
        for (int r = 0; r < 16; ++r) acc[r] = fmaf(xw[t], wih_r[r], bias_r[r]);

        // D = Whh * h^T: all four split cross terms, both K-halves (8 MFMA)
        acc = mfma_bf16(A1h, B1h, acc);
        acc = mfma_bf16(A2h, B2h, acc);
        acc = mfma_bf16(A1h, B1l, acc);
        acc = mfma_bf16(A2h, B2l, acc);
        acc = mfma_bf16(A1l, B1h, acc);
        acc = mfma_bf16(A2l, B2h, acc);
        acc = mfma_bf16(A1l, B1l, acc);
        acc = mfma_bf16(A2l, B2l, acc);

        #pragma unroll
        for (int r = 0; r < 16; ++r) h[r] = fast_tanh(acc[r]);

        // output head: o[b,t] = sum_j h[j]*Wout[j] + bout (partner holds other 16 rows)
        float o = 0.f;
        #pragma unroll
        for (int r = 0; r < 16; ++r) o = fmaf(h[r], wout_r[r], o);
        o += __shfl_xor(o, 32);
        if (lane < 32) out[(size_t)b * RNN_T + t] = o + bo;

        if (t < RNN_T - 1) {
            // Rebuild B fragments for next step from D-layout h.
            // hi=0 lane rows: {0-3,8-11,16-19,24-27}; hi=1: {4-7,12-15,20-23,28-31}.
            // Packed pairs S[p]=(h[2p],h[2p+1]).
            unsigned Sh[8], Sl[8];
            #pragma unroll
            for (int p = 0; p < 8; ++p) {
                float f0 = h[2 * p], f1 = h[2 * p + 1];
                Sh[p] = pack_hi_pair(f0, f1);
                Sl[p] = pack_hi_pair(f0 - trunc_bf16_f32(f0),
                                     f1 - trunc_bf16_f32(f1));
            }
            // Exchange: lo lane sends S[2],S[3],S[6],S[7] (rows 8-11,24-27);
            // hi lane sends S[0],S[1],S[4],S[5] (rows 4-7,20-23).
            unsigned r0h = __shfl_xor(lo_lane ? Sh[2] : Sh[0], 32);
            unsigned r1h = __shfl_xor(lo_lane ? Sh[3] : Sh[1], 32);
            unsigned r2h = __shfl_xor(lo_lane ? Sh[6] : Sh[4], 32);
            unsigned r3h = __shfl_xor(lo_lane ? Sh[7] : Sh[5], 32);
            unsigned r0l = __shfl_xor(lo_lane ? Sl[2] : Sl[0], 32);
            unsigned r1l = __shfl_xor(lo_lane ? Sl[3] : Sl[1], 32);
            unsigned r2l = __shfl_xor(lo_lane ? Sl[6] : Sl[4], 32);
            unsigned r3l = __shfl_xor(lo_lane ? Sl[7] : Sl[5], 32);
            // lo-lane B1 = rows (0,1),(2,3),(4,5),(6,7); hi-lane B1 = rows 8..15
            B1h[0] = lo_lane ? Sh[0] : r0h;  B1h[1] = lo_lane ? Sh[1] : r1h;
            B1h[2] = lo_lane ? r0h : Sh[2];  B1h[3] = lo_lane ? r1h : Sh[3];
            B2h[0] = lo_lane ? Sh[4] : r2h;  B2h[1] = lo_lane ? Sh[5] : r3h;
            B2h[2] = lo_lane ? r2h : Sh[6];  B2h[3] = lo_lane ? r3h : Sh[7];
            B1l[0] = lo_lane ? Sl[0] : r0l;  B1l[1] = lo_lane ? Sl[1] : r1l;
            B1l[2] = lo_lane ? r0l : Sl[2];  B1l[3] = lo_lane ? r1l : Sl[3];
            B2l[0] = lo_lane ? Sl[4] : r2l;  B2l[1] = lo_lane ? Sl[5] : r3l;
            B2l[2] = lo_lane ? r2l : Sl[6];  B2l[3] = lo_lane ? r3l : Sl[7];
        }
    }

    // ---- final hidden state: rows 8q+4*hi+0..3 are h[4q..4q+3], contiguous ----
    float* hl = out + (size_t)B * RNN_T + (size_t)b * RNN_H;
    #pragma unroll
    for (int q = 0; q < 4; ++q) {
        float4 v;
        v.x = h[4 * q + 0]; v.y = h[4 * q + 1];
        v.z = h[4 * q + 2]; v.w = h[4 * q + 3];
        *reinterpret_cast<float4*>(hl + 8 * q + 4 * hi) = v;
    }
}

extern "C" void kernel_launch(void* const* d_in, const int* in_sizes, int n_in,
                              void* d_out, int out_size, void* d_ws, size_t ws_size,
                              hipStream_t stream) {
    const float* x    = (const float*)d_in[0];
    const float* h0   = (const float*)d_in[1];
    const float* Wih  = (const float*)d_in[2];
    const float* Whh  = (const float*)d_in[3];
    const float* bih  = (const float*)d_in[4];
    const float* bhh  = (const float*)d_in[5];
    const float* Wout = (const float*)d_in[6];
    const float* bout = (const float*)d_in[7];
    float* out = (float*)d_out;

    const int B = in_sizes[1] / RNN_H;     // 262144
    dim3 grid(B / 128);                    // 4 waves/block, 32 batches/wave
    dim3 block(256);
    hipLaunchKernelGGL(rnn_mfma, grid, block, 0, stream,
                       x, h0, Wih, Whh, bih, bhh, Wout, bout, out, B);
}